// Round 4
// baseline (92.845 us; speedup 1.0000x reference)
//
#include <hip/hip_runtime.h>
#include <hip/hip_cooperative_groups.h>
#include <math.h>

namespace cg = cooperative_groups;

#define Bq 4
#define Kq 16
#define Nq 2048
#define Dq 256

typedef float f32x4 __attribute__((ext_vector_type(4)));
typedef short s16x8 __attribute__((ext_vector_type(8)));
typedef unsigned int u32;

union frag_u { s16x8 v; u32 w[4]; };

static __device__ __forceinline__ u32 cvtpk(float a, float b) {
    u32 r;
    asm("v_cvt_pk_bf16_f32 %0, %1, %2" : "=v"(r) : "v"(a), "v"(b));
    return r;
}

// 2 floats -> packed hi-bf16 word + packed lo-bf16 word (hi/lo split)
static __device__ __forceinline__ void cvt2(float a, float b, u32* hw, u32* lw) {
    const u32 h = cvtpk(a, b);
    const float h0 = __uint_as_float(h << 16);
    const float h1 = __uint_as_float(h & 0xFFFF0000u);
    *hw = h;
    *lw = cvtpk(a - h0, b - h1);
}

static __device__ __forceinline__ void conv8(const float4 a, const float4 b,
                                             s16x8* hi, s16x8* lo) {
    frag_u H, L;
    cvt2(a.x, a.y, &H.w[0], &L.w[0]);
    cvt2(a.z, a.w, &H.w[1], &L.w[1]);
    cvt2(b.x, b.y, &H.w[2], &L.w[2]);
    cvt2(b.z, b.w, &H.w[3], &L.w[3]);
    *hi = H.v; *lo = L.v;
}

#define MFMA(A, B, C) __builtin_amdgcn_mfma_f32_16x16x32_bf16((A), (B), (C), 0, 0, 0)

// Single cooperative kernel: 512 blocks x 256 threads (exactly co-resident at
// 2 blocks/CU). Wave w of each block solves img matrix w (redundant across
// blocks; img is cache-resident) and text matrix n = 4*blk + w, writes logits
// to ws, grid-syncs, then blocks 0..31 compute the row log-softmax (8 blocks
// per row, redundant row reduction, disjoint 256-wide output slices).
__global__ __launch_bounds__(256, 2) void fused_all(const float* __restrict__ img,
                                                    const float* __restrict__ text,
                                                    const float* __restrict__ r,
                                                    const float* __restrict__ alp,
                                                    const float* __restrict__ scale,
                                                    const float* __restrict__ lsc,
                                                    float* __restrict__ logits,
                                                    float* __restrict__ out) {
    __shared__ __align__(16) float AugI[4][Kq][34];
    __shared__ __align__(16) float AugT[4][Kq][34];
    __shared__ __align__(16) f32x4 shS1[4][64];
    __shared__ __align__(16) f32x4 shGI[4][64];
    __shared__ float shRed[4];

    const int tid  = threadIdx.x;
    const int w    = tid >> 6, lane = tid & 63;
    const int arow = lane & 15, kgrp = lane >> 4, ccol = arow;
    const int n    = blockIdx.x * 4 + w;

    const float lamI = (float(Bq) / float(Dq)) * expf(r[0]) + 1e-6f;
    const float rhoI = expf(r[1]);
    const float lamT = (float(Nq) / float(Dq)) * expf(r[2]) + 1e-6f;
    const float rhoT = expf(r[3]);

    // ---- load both matrices' fragments (img from cache, text from HBM) ----
    const float* baseI = img  + w * (Kq * Dq) + arow * Dq + kgrp * 8;
    const float* baseT = text + n * (Kq * Dq) + arow * Dq + kgrp * 8;
    float4 xi[16], xt[16];
#pragma unroll
    for (int c = 0; c < 8; ++c) {
        xi[2 * c]     = *reinterpret_cast<const float4*>(baseI + c * 32);
        xi[2 * c + 1] = *reinterpret_cast<const float4*>(baseI + c * 32 + 4);
        xt[2 * c]     = *reinterpret_cast<const float4*>(baseT + c * 32);
        xt[2 * c + 1] = *reinterpret_cast<const float4*>(baseT + c * 32 + 4);
    }

    // ---- Grams via MFMA (hi/lo bf16 split) ----
    f32x4 gI = {0.f, 0.f, 0.f, 0.f}, gT = {0.f, 0.f, 0.f, 0.f};
#pragma unroll
    for (int c = 0; c < 8; ++c) {
        s16x8 hi, lo;
        conv8(xi[2 * c], xi[2 * c + 1], &hi, &lo);
        gI = MFMA(hi, hi, gI); gI = MFMA(hi, lo, gI); gI = MFMA(lo, hi, gI);
        conv8(xt[2 * c], xt[2 * c + 1], &hi, &lo);
        gT = MFMA(hi, hi, gT); gT = MFMA(hi, lo, gT); gT = MFMA(lo, hi, gT);
    }

    // ---- build augmented systems (interleaved A|RHS) ----
    float (*AI)[34] = AugI[w];
    float (*AT)[34] = AugT[w];
#pragma unroll
    for (int q = 0; q < 4; ++q) {
        const int rr = kgrp * 4 + q;
        const float dI = (rr == ccol) ? lamI : 0.f;
        const float dT = (rr == ccol) ? lamT : 0.f;
        float2 pI; pI.x = gI[q] + dI; pI.y = (rhoI - 1.f) * gI[q] - dI;
        float2 pT; pT.x = gT[q] + dT; pT.y = (rhoT - 1.f) * gT[q] - dT;
        *reinterpret_cast<float2*>(&AI[rr][2 * ccol]) = pI;
        *reinterpret_cast<float2*>(&AT[rr][2 * ccol]) = pT;
    }
    __builtin_amdgcn_wave_barrier();

    // ---- dual wave-synchronous Gauss-Jordan (independent chains interleave) ----
    for (int k = 0; k < Kq; ++k) {
        const float2 pvI = *reinterpret_cast<const float2*>(&AI[k][2 * k]);
        const float2 pvT = *reinterpret_cast<const float2*>(&AT[k][2 * k]);
        const float2 pkI = *reinterpret_cast<const float2*>(&AI[k][2 * ccol]);
        const float2 pkT = *reinterpret_cast<const float2*>(&AT[k][2 * ccol]);
        const float piI = 1.f / pvI.x;
        const float piT = 1.f / pvT.x;
        float facI[4], facT[4];
#pragma unroll
        for (int q = 0; q < 4; ++q) {
            facI[q] = AI[kgrp * 4 + q][2 * k];
            facT[q] = AT[kgrp * 4 + q][2 * k];
        }
        __builtin_amdgcn_wave_barrier();
#pragma unroll
        for (int q = 0; q < 4; ++q) {
            const int rr = kgrp * 4 + q;
            float2 cI = *reinterpret_cast<const float2*>(&AI[rr][2 * ccol]);
            float2 cT = *reinterpret_cast<const float2*>(&AT[rr][2 * ccol]);
            const float fI = facI[q] * piI;
            const float fT = facT[q] * piT;
            float2 nI, nT;
            nI.x = (rr == k) ? pkI.x * piI : cI.x - fI * pkI.x;
            nI.y = (rr == k) ? pkI.y * piI : cI.y - fI * pkI.y;
            nT.x = (rr == k) ? pkT.x * piT : cT.x - fT * pkT.x;
            nT.y = (rr == k) ? pkT.y * piT : cT.y - fT * pkT.y;
            *reinterpret_cast<float2*>(&AI[rr][2 * ccol]) = nI;
            *reinterpret_cast<float2*>(&AT[rr][2 * ccol]) = nT;
        }
        __builtin_amdgcn_wave_barrier();
    }

    // ---- S = M*M via MFMA (M symmetric, K=16 zero-padded to 32) ----
    frag_u HImg, LImg, HTxt, LTxt;
#pragma unroll
    for (int e = 0; e < 8; e += 2) {
        const int kk = (kgrp & 1) * 8 + e;
        const bool vld = (lane < 32);
        const float i0 = vld ? AI[arow][2 * kk + 1]       : 0.f;
        const float i1 = vld ? AI[arow][2 * (kk + 1) + 1] : 0.f;
        const float t0 = vld ? AT[arow][2 * kk + 1]       : 0.f;
        const float t1 = vld ? AT[arow][2 * (kk + 1) + 1] : 0.f;
        cvt2(i0, i1, &HImg.w[e >> 1], &LImg.w[e >> 1]);
        cvt2(t0, t1, &HTxt.w[e >> 1], &LTxt.w[e >> 1]);
    }
    f32x4 sI = {0.f, 0.f, 0.f, 0.f}, sT = {0.f, 0.f, 0.f, 0.f};
    sI = MFMA(HImg.v, HImg.v, sI); sI = MFMA(HImg.v, LImg.v, sI); sI = MFMA(LImg.v, HImg.v, sI);
    sT = MFMA(HTxt.v, HTxt.v, sT); sT = MFMA(HTxt.v, LTxt.v, sT); sT = MFMA(LTxt.v, HTxt.v, sT);

    // ---- block-local exchange of img results, then dots ----
    shS1[w][lane] = sI;
    shGI[w][lane] = gI;
    __syncthreads();

    float p[8];
#pragma unroll
    for (int b = 0; b < 4; ++b) {
        const f32x4 s1 = shS1[b][lane];
        const f32x4 gi = shGI[b][lane];
        p[b]     = s1.x * gT.x + s1.y * gT.y + s1.z * gT.z + s1.w * gT.w;  // <S1[b], G_T>
        p[4 + b] = gi.x * sT.x + gi.y * sT.y + gi.z * sT.z + gi.w * sT.w;  // <S2, G_I[b]>
    }
#pragma unroll
    for (int off = 32; off; off >>= 1) {
#pragma unroll
        for (int q = 0; q < 8; ++q) p[q] += __shfl_down(p[q], off, 64);
    }
    if (lane == 0) {
        const float a = alp[0], sc = scale[0];
#pragma unroll
        for (int b = 0; b < 4; ++b) {
            const float d1 = -p[b] * (1.f / Kq);
            const float d2 = -p[4 + b] * (1.f / Kq);
            logits[b * Nq + n] = sc * (a * d1 + (1.f - a) * d2);
        }
    }

    // ---- grid-wide sync, then in-kernel log-softmax ----
    __threadfence();
    cg::this_grid().sync();
    if (blockIdx.x >= 32) return;

    const int b   = blockIdx.x >> 3;   // row
    const int seg = blockIdx.x & 7;    // 256-wide output slice
    const float* row = logits + b * Nq;
    float v[8];
    float mx = -INFINITY;
#pragma unroll
    for (int q = 0; q < 8; ++q) {
        v[q] = row[tid + q * 256];
        mx = fmaxf(mx, v[q]);
    }
#pragma unroll
    for (int off = 32; off; off >>= 1) mx = fmaxf(mx, __shfl_down(mx, off, 64));
    if (lane == 0) shRed[w] = mx;
    __syncthreads();
    mx = fmaxf(fmaxf(shRed[0], shRed[1]), fmaxf(shRed[2], shRed[3]));

    float sum = 0.f;
#pragma unroll
    for (int q = 0; q < 8; ++q) sum += expf(v[q] - mx);
#pragma unroll
    for (int off = 32; off; off >>= 1) sum += __shfl_down(sum, off, 64);
    __syncthreads();
    if (lane == 0) shRed[w] = sum;
    __syncthreads();
    sum = shRed[0] + shRed[1] + shRed[2] + shRed[3];

    const float lse = mx + logf(sum);
    out[b * Nq + seg * 256 + tid] = v[seg] - lse;
    if (blockIdx.x == 0 && tid == 0) out[Bq * Nq] = 1.f / (1.f + expf(-lsc[0]));
}

extern "C" void kernel_launch(void* const* d_in, const int* in_sizes, int n_in,
                              void* d_out, int out_size, void* d_ws, size_t ws_size,
                              hipStream_t stream) {
    const float* img   = (const float*)d_in[0];
    const float* text  = (const float*)d_in[1];
    const float* r     = (const float*)d_in[2];
    const float* alp   = (const float*)d_in[3];
    const float* scale = (const float*)d_in[4];
    const float* lsc   = (const float*)d_in[5];
    float* ws  = (float*)d_ws;   // logits: 4*2048 floats
    float* out = (float*)d_out;

    void* args[] = {(void*)&img, (void*)&text, (void*)&r, (void*)&alp,
                    (void*)&scale, (void*)&lsc, (void*)&ws, (void*)&out};
    hipLaunchCooperativeKernel((void*)fused_all, dim3(Nq / 4), dim3(256),
                               args, 0, stream);
}

// Round 5
// 24.318 us; speedup vs baseline: 3.8180x; 3.8180x over previous
//
#include <hip/hip_runtime.h>
#include <math.h>

#define Bq 4
#define Kq 16
#define Nq 2048
#define Dq 256

typedef float f32x4 __attribute__((ext_vector_type(4)));
typedef short s16x8 __attribute__((ext_vector_type(8)));
typedef unsigned int u32;

union frag_u { s16x8 v; u32 w[4]; };

static __device__ __forceinline__ u32 cvtpk(float a, float b) {
    u32 r;
    asm("v_cvt_pk_bf16_f32 %0, %1, %2" : "=v"(r) : "v"(a), "v"(b));
    return r;
}

// 2 floats -> packed hi-bf16 word + packed lo-bf16 word (hi/lo split)
static __device__ __forceinline__ void cvt2(float a, float b, u32* hw, u32* lw) {
    const u32 h = cvtpk(a, b);
    const float h0 = __uint_as_float(h << 16);
    const float h1 = __uint_as_float(h & 0xFFFF0000u);
    *hw = h;
    *lw = cvtpk(a - h0, b - h1);
}

static __device__ __forceinline__ void conv8(const float4 a, const float4 b,
                                             s16x8* hi, s16x8* lo) {
    frag_u H, L;
    cvt2(a.x, a.y, &H.w[0], &L.w[0]);
    cvt2(a.z, a.w, &H.w[1], &L.w[1]);
    cvt2(b.x, b.y, &H.w[2], &L.w[2]);
    cvt2(b.z, b.w, &H.w[3], &L.w[3]);
    *hi = H.v; *lo = L.v;
}

#define MFMA(A, B, C) __builtin_amdgcn_mfma_f32_16x16x32_bf16((A), (B), (C), 0, 0, 0)

// 512 blocks x 256 threads, exactly 2 blocks/CU (launch_bounds(256,2) lifts the
// VGPR cap to 256 so all 32 float4 loads stay materialized and in flight).
// Wave w solves img matrix w (redundant across blocks; img is L2-resident) and
// text matrix n = 4*blk + w. Load order: img first, text second (vmcnt is
// in-order, so img conversion only drains img loads and overlaps text flight).
__global__ __launch_bounds__(256, 2) void fused_kernel(const float* __restrict__ img,
                                                       const float* __restrict__ text,
                                                       const float* __restrict__ r,
                                                       const float* __restrict__ alp,
                                                       const float* __restrict__ scale,
                                                       float* __restrict__ logits) {
    __shared__ __align__(16) float AugI[4][Kq][34];
    __shared__ __align__(16) float AugT[4][Kq][34];
    __shared__ __align__(16) f32x4 shS1[4][64];
    __shared__ __align__(16) f32x4 shGI[4][64];

    const int tid  = threadIdx.x;
    const int w    = tid >> 6, lane = tid & 63;
    const int arow = lane & 15, kgrp = lane >> 4, ccol = arow;
    const int n    = blockIdx.x * 4 + w;

    // ---- issue ALL loads first: img (L2) then text (HBM); pin with sched_barrier ----
    const float* baseI = img  + w * (Kq * Dq) + arow * Dq + kgrp * 8;
    const float* baseT = text + n * (Kq * Dq) + arow * Dq + kgrp * 8;
    float4 xi[16], xt[16];
#pragma unroll
    for (int c = 0; c < 8; ++c) {
        xi[2 * c]     = *reinterpret_cast<const float4*>(baseI + c * 32);
        xi[2 * c + 1] = *reinterpret_cast<const float4*>(baseI + c * 32 + 4);
    }
#pragma unroll
    for (int c = 0; c < 8; ++c) {
        xt[2 * c]     = *reinterpret_cast<const float4*>(baseT + c * 32);
        xt[2 * c + 1] = *reinterpret_cast<const float4*>(baseT + c * 32 + 4);
    }
    __builtin_amdgcn_sched_barrier(0);

    const float lamI = (float(Bq) / float(Dq)) * expf(r[0]) + 1e-6f;
    const float rhoI = expf(r[1]);
    const float lamT = (float(Nq) / float(Dq)) * expf(r[2]) + 1e-6f;
    const float rhoT = expf(r[3]);

    // ---- img Gram via MFMA (hi/lo bf16 split) while text loads are in flight ----
    f32x4 gI = {0.f, 0.f, 0.f, 0.f};
#pragma unroll
    for (int c = 0; c < 8; ++c) {
        s16x8 hi, lo;
        conv8(xi[2 * c], xi[2 * c + 1], &hi, &lo);
        gI = MFMA(hi, hi, gI); gI = MFMA(hi, lo, gI); gI = MFMA(lo, hi, gI);
    }
    // ---- text Gram ----
    f32x4 gT = {0.f, 0.f, 0.f, 0.f};
#pragma unroll
    for (int c = 0; c < 8; ++c) {
        s16x8 hi, lo;
        conv8(xt[2 * c], xt[2 * c + 1], &hi, &lo);
        gT = MFMA(hi, hi, gT); gT = MFMA(hi, lo, gT); gT = MFMA(lo, hi, gT);
    }

    // ---- build augmented systems (interleaved A|RHS) ----
    float (*AI)[34] = AugI[w];
    float (*AT)[34] = AugT[w];
#pragma unroll
    for (int q = 0; q < 4; ++q) {
        const int rr = kgrp * 4 + q;
        const float dI = (rr == ccol) ? lamI : 0.f;
        const float dT = (rr == ccol) ? lamT : 0.f;
        float2 pI; pI.x = gI[q] + dI; pI.y = (rhoI - 1.f) * gI[q] - dI;
        float2 pT; pT.x = gT[q] + dT; pT.y = (rhoT - 1.f) * gT[q] - dT;
        *reinterpret_cast<float2*>(&AI[rr][2 * ccol]) = pI;
        *reinterpret_cast<float2*>(&AT[rr][2 * ccol]) = pT;
    }
    __builtin_amdgcn_wave_barrier();

    // ---- dual wave-synchronous Gauss-Jordan (independent chains interleave) ----
    for (int k = 0; k < Kq; ++k) {
        const float2 pvI = *reinterpret_cast<const float2*>(&AI[k][2 * k]);
        const float2 pvT = *reinterpret_cast<const float2*>(&AT[k][2 * k]);
        const float2 pkI = *reinterpret_cast<const float2*>(&AI[k][2 * ccol]);
        const float2 pkT = *reinterpret_cast<const float2*>(&AT[k][2 * ccol]);
        const float piI = 1.f / pvI.x;
        const float piT = 1.f / pvT.x;
        float facI[4], facT[4];
#pragma unroll
        for (int q = 0; q < 4; ++q) {
            facI[q] = AI[kgrp * 4 + q][2 * k];
            facT[q] = AT[kgrp * 4 + q][2 * k];
        }
        __builtin_amdgcn_wave_barrier();
#pragma unroll
        for (int q = 0; q < 4; ++q) {
            const int rr = kgrp * 4 + q;
            float2 cI = *reinterpret_cast<const float2*>(&AI[rr][2 * ccol]);
            float2 cT = *reinterpret_cast<const float2*>(&AT[rr][2 * ccol]);
            const float fI = facI[q] * piI;
            const float fT = facT[q] * piT;
            float2 nI, nT;
            nI.x = (rr == k) ? pkI.x * piI : cI.x - fI * pkI.x;
            nI.y = (rr == k) ? pkI.y * piI : cI.y - fI * pkI.y;
            nT.x = (rr == k) ? pkT.x * piT : cT.x - fT * pkT.x;
            nT.y = (rr == k) ? pkT.y * piT : cT.y - fT * pkT.y;
            *reinterpret_cast<float2*>(&AI[rr][2 * ccol]) = nI;
            *reinterpret_cast<float2*>(&AT[rr][2 * ccol]) = nT;
        }
        __builtin_amdgcn_wave_barrier();
    }

    // ---- S = M*M via MFMA (M symmetric, K=16 zero-padded to 32) ----
    frag_u HImg, LImg, HTxt, LTxt;
#pragma unroll
    for (int e = 0; e < 8; e += 2) {
        const int kk = (kgrp & 1) * 8 + e;
        const bool vld = (lane < 32);
        const float i0 = vld ? AI[arow][2 * kk + 1]       : 0.f;
        const float i1 = vld ? AI[arow][2 * (kk + 1) + 1] : 0.f;
        const float t0 = vld ? AT[arow][2 * kk + 1]       : 0.f;
        const float t1 = vld ? AT[arow][2 * (kk + 1) + 1] : 0.f;
        cvt2(i0, i1, &HImg.w[e >> 1], &LImg.w[e >> 1]);
        cvt2(t0, t1, &HTxt.w[e >> 1], &LTxt.w[e >> 1]);
    }
    f32x4 sI = {0.f, 0.f, 0.f, 0.f}, sT = {0.f, 0.f, 0.f, 0.f};
    sI = MFMA(HImg.v, HImg.v, sI); sI = MFMA(HImg.v, LImg.v, sI); sI = MFMA(LImg.v, HImg.v, sI);
    sT = MFMA(HTxt.v, HTxt.v, sT); sT = MFMA(HTxt.v, LTxt.v, sT); sT = MFMA(LTxt.v, HTxt.v, sT);

    // ---- block-local exchange of img results, then dots ----
    shS1[w][lane] = sI;
    shGI[w][lane] = gI;
    __syncthreads();

    float p[8];
#pragma unroll
    for (int b = 0; b < 4; ++b) {
        const f32x4 s1 = shS1[b][lane];
        const f32x4 gi = shGI[b][lane];
        p[b]     = s1.x * gT.x + s1.y * gT.y + s1.z * gT.z + s1.w * gT.w;  // <S1[b], G_T>
        p[4 + b] = gi.x * sT.x + gi.y * sT.y + gi.z * sT.z + gi.w * sT.w;  // <S2, G_I[b]>
    }
#pragma unroll
    for (int off = 32; off; off >>= 1) {
#pragma unroll
        for (int q = 0; q < 8; ++q) p[q] += __shfl_down(p[q], off, 64);
    }
    if (lane == 0) {
        const float a = alp[0], sc = scale[0];
#pragma unroll
        for (int b = 0; b < 4; ++b) {
            const float d1 = -p[b] * (1.f / Kq);
            const float d2 = -p[4 + b] * (1.f / Kq);
            logits[b * Nq + n] = sc * (a * d1 + (1.f - a) * d2);
        }
    }
}

__global__ __launch_bounds__(256) void softmax_kernel(const float* __restrict__ logits,
                                                      const float* __restrict__ lsc,
                                                      float* __restrict__ out) {
    const int b   = blockIdx.x;
    const int tid = threadIdx.x;
    const float* row = logits + b * Nq;
    __shared__ float sh[4];
    float v[8];
    float mx = -INFINITY;
#pragma unroll
    for (int q = 0; q < 8; ++q) {
        v[q] = row[tid + q * 256];
        mx = fmaxf(mx, v[q]);
    }
#pragma unroll
    for (int off = 32; off; off >>= 1) mx = fmaxf(mx, __shfl_down(mx, off, 64));
    if ((tid & 63) == 0) sh[tid >> 6] = mx;
    __syncthreads();
    mx = fmaxf(fmaxf(sh[0], sh[1]), fmaxf(sh[2], sh[3]));

    float sum = 0.f;
#pragma unroll
    for (int q = 0; q < 8; ++q) sum += expf(v[q] - mx);
#pragma unroll
    for (int off = 32; off; off >>= 1) sum += __shfl_down(sum, off, 64);
    __syncthreads();
    if ((tid & 63) == 0) sh[tid >> 6] = sum;
    __syncthreads();
    sum = sh[0] + sh[1] + sh[2] + sh[3];

    const float lse = mx + logf(sum);
#pragma unroll
    for (int q = 0; q < 8; ++q) out[b * Nq + tid + q * 256] = v[q] - lse;
    if (b == 0 && tid == 0) out[Bq * Nq] = 1.f / (1.f + expf(-lsc[0]));
}

extern "C" void kernel_launch(void* const* d_in, const int* in_sizes, int n_in,
                              void* d_out, int out_size, void* d_ws, size_t ws_size,
                              hipStream_t stream) {
    const float* img   = (const float*)d_in[0];
    const float* text  = (const float*)d_in[1];
    const float* r     = (const float*)d_in[2];
    const float* alp   = (const float*)d_in[3];
    const float* scale = (const float*)d_in[4];
    const float* lsc   = (const float*)d_in[5];
    float* ws  = (float*)d_ws;   // logits: 4*2048 floats
    float* out = (float*)d_out;

    fused_kernel<<<Nq / 4, 256, 0, stream>>>(img, text, r, alp, scale, ws);
    softmax_kernel<<<Bq, 256, 0, stream>>>(ws, lsc, out);
}

// Round 6
// 22.926 us; speedup vs baseline: 4.0497x; 1.0607x over previous
//
#include <hip/hip_runtime.h>
#include <math.h>

#define Bq 4
#define Kq 16
#define Nq 2048
#define Dq 256

typedef float f32x4 __attribute__((ext_vector_type(4)));
typedef short s16x8 __attribute__((ext_vector_type(8)));
typedef unsigned int u32;

union frag_u { s16x8 v; u32 w[4]; };

static __device__ __forceinline__ u32 cvtpk(float a, float b) {
    u32 r;
    asm("v_cvt_pk_bf16_f32 %0, %1, %2" : "=v"(r) : "v"(a), "v"(b));
    return r;
}

// 2 floats -> packed hi-bf16 word + packed lo-bf16 word (hi/lo split)
static __device__ __forceinline__ void cvt2(float a, float b, u32* hw, u32* lw) {
    const u32 h = cvtpk(a, b);
    const float h0 = __uint_as_float(h << 16);
    const float h1 = __uint_as_float(h & 0xFFFF0000u);
    *hw = h;
    *lw = cvtpk(a - h0, b - h1);
}

static __device__ __forceinline__ void conv8(const float4 a, const float4 b,
                                             s16x8* hi, s16x8* lo) {
    frag_u H, L;
    cvt2(a.x, a.y, &H.w[0], &L.w[0]);
    cvt2(a.z, a.w, &H.w[1], &L.w[1]);
    cvt2(b.x, b.y, &H.w[2], &L.w[2]);
    cvt2(b.z, b.w, &H.w[3], &L.w[3]);
    *hi = H.v; *lo = L.v;
}

static __device__ __forceinline__ float rdlane(float x, int l) {
    return __uint_as_float((u32)__builtin_amdgcn_readlane((int)__float_as_uint(x), l));
}

#define MFMA(A, B, C) __builtin_amdgcn_mfma_f32_16x16x32_bf16((A), (B), (C), 0, 0, 0)

// 512 blocks x 256 threads (2 blocks/CU). Wave w: img matrix w (redundant,
// L2-resident) + text matrix n=4*blk+w. Gram + S=M^2 via MFMA (hi/lo bf16
// split). Gauss-Jordan fully in REGISTERS: lane j owns column j of (A|RHS);
// lanes 0-15 = img system, 16-31 = text system (32-63 dup). Column-k
// broadcast via v_readlane (static index, full unroll) - zero LDS in the loop.
__global__ __launch_bounds__(256, 2) void fused_kernel(const float* __restrict__ img,
                                                       const float* __restrict__ text,
                                                       const float* __restrict__ r,
                                                       const float* __restrict__ alp,
                                                       const float* __restrict__ scale,
                                                       float* __restrict__ logits) {
    // per-wave scratch: entry transpose Gc[2][16][20], exit Mr[2][16][20] (reused)
    __shared__ __align__(16) float scratch[4][2][16][20];
    __shared__ __align__(16) f32x4 shS1[4][64];
    __shared__ __align__(16) f32x4 shGI[4][64];

    const int tid  = threadIdx.x;
    const int w    = tid >> 6, lane = tid & 63;
    const int arow = lane & 15, kgrp = lane >> 4, ccol = arow;
    const int n    = blockIdx.x * 4 + w;
    const bool isT = (lane & 16) != 0;   // system of this lane's 16-group (0-15/32-47: img, 16-31/48-63: text)
    const int  sys = isT ? 1 : 0;

    // ---- issue ALL loads first: img (L2) then text (HBM); pin with sched_barrier ----
    const float* baseI = img  + w * (Kq * Dq) + arow * Dq + kgrp * 8;
    const float* baseT = text + n * (Kq * Dq) + arow * Dq + kgrp * 8;
    float4 xi[16], xt[16];
#pragma unroll
    for (int c = 0; c < 8; ++c) {
        xi[2 * c]     = *reinterpret_cast<const float4*>(baseI + c * 32);
        xi[2 * c + 1] = *reinterpret_cast<const float4*>(baseI + c * 32 + 4);
    }
#pragma unroll
    for (int c = 0; c < 8; ++c) {
        xt[2 * c]     = *reinterpret_cast<const float4*>(baseT + c * 32);
        xt[2 * c + 1] = *reinterpret_cast<const float4*>(baseT + c * 32 + 4);
    }
    __builtin_amdgcn_sched_barrier(0);

    const float lamI = (float(Bq) / float(Dq)) * expf(r[0]) + 1e-6f;
    const float rhoI = expf(r[1]);
    const float lamT = (float(Nq) / float(Dq)) * expf(r[2]) + 1e-6f;
    const float rhoT = expf(r[3]);

    // ---- img Gram via MFMA while text loads are in flight ----
    f32x4 gI = {0.f, 0.f, 0.f, 0.f};
#pragma unroll
    for (int c = 0; c < 8; ++c) {
        s16x8 hi, lo;
        conv8(xi[2 * c], xi[2 * c + 1], &hi, &lo);
        gI = MFMA(hi, hi, gI); gI = MFMA(hi, lo, gI); gI = MFMA(lo, hi, gI);
    }
    // ---- text Gram ----
    f32x4 gT = {0.f, 0.f, 0.f, 0.f};
#pragma unroll
    for (int c = 0; c < 8; ++c) {
        s16x8 hi, lo;
        conv8(xt[2 * c], xt[2 * c + 1], &hi, &lo);
        gT = MFMA(hi, hi, gT); gT = MFMA(hi, lo, gT); gT = MFMA(lo, hi, gT);
    }

    // ---- transpose Gram C/D layout -> column ownership (one LDS round trip) ----
    float (*Gc)[16][20] = scratch[w];   // [sys][col][row(0..15) + pad]
    *reinterpret_cast<f32x4*>(&Gc[0][ccol][kgrp * 4]) = gI;
    *reinterpret_cast<f32x4*>(&Gc[1][ccol][kgrp * 4]) = gT;
    __builtin_amdgcn_wave_barrier();

    // lane j of each 16-group owns column j of its system
    const int j = arow;
    float A[16], rhs[16];
    {
        const float lam = isT ? lamT : lamI;
        const float rho = isT ? rhoT : rhoI;
        const float* col = &Gc[sys][j][0];
        const f32x4 c0 = *reinterpret_cast<const f32x4*>(col + 0);
        const f32x4 c1 = *reinterpret_cast<const f32x4*>(col + 4);
        const f32x4 c2 = *reinterpret_cast<const f32x4*>(col + 8);
        const f32x4 c3 = *reinterpret_cast<const f32x4*>(col + 12);
        float g[16];
#pragma unroll
        for (int q = 0; q < 4; ++q) {
            g[q] = c0[q]; g[4 + q] = c1[q]; g[8 + q] = c2[q]; g[12 + q] = c3[q];
        }
#pragma unroll
        for (int i = 0; i < 16; ++i) {
            const float dv = (i == j) ? lam : 0.f;
            A[i]   = g[i] + dv;
            rhs[i] = (rho - 1.f) * g[i] - dv;
        }
    }
    __builtin_amdgcn_wave_barrier();   // Gc reads complete before scratch reuse

    // ---- register Gauss-Jordan, fully unrolled (no LDS, no barriers) ----
#pragma unroll
    for (int k = 0; k < Kq; ++k) {
        const float pI = rdlane(A[k], k);
        const float pT = rdlane(A[k], 16 + k);
        const float pinv = 1.0f / (isT ? pT : pI);
        A[k]   *= pinv;
        rhs[k] *= pinv;
#pragma unroll
        for (int i = 0; i < 16; ++i) {
            if (i == k) continue;
            const float uI = rdlane(A[i], k);
            const float uT = rdlane(A[i], 16 + k);
            const float fac = isT ? uT : uI;
            A[i]   = fmaf(-fac, A[k],   A[i]);
            rhs[i] = fmaf(-fac, rhs[k], rhs[i]);
        }
    }
    // rhs[] = column j of M (M symmetric => also row j)

    // ---- write M row-major for frag build (one LDS round trip) ----
    float (*Mr)[16][20] = scratch[w];   // [sys][row][col + pad]
#pragma unroll
    for (int i = 0; i < 16; ++i) Mr[sys][i][j] = rhs[i];
    __builtin_amdgcn_wave_barrier();

    // ---- S = M*M via MFMA (K=16 zero-padded to 32) ----
    frag_u HImg, LImg, HTxt, LTxt;
#pragma unroll
    for (int e = 0; e < 8; e += 2) {
        const int kk = (kgrp & 1) * 8 + e;
        const bool vld = (lane < 32);
        const float i0 = vld ? Mr[0][arow][kk]     : 0.f;
        const float i1 = vld ? Mr[0][arow][kk + 1] : 0.f;
        const float t0 = vld ? Mr[1][arow][kk]     : 0.f;
        const float t1 = vld ? Mr[1][arow][kk + 1] : 0.f;
        cvt2(i0, i1, &HImg.w[e >> 1], &LImg.w[e >> 1]);
        cvt2(t0, t1, &HTxt.w[e >> 1], &LTxt.w[e >> 1]);
    }
    f32x4 sI = {0.f, 0.f, 0.f, 0.f}, sT = {0.f, 0.f, 0.f, 0.f};
    sI = MFMA(HImg.v, HImg.v, sI); sI = MFMA(HImg.v, LImg.v, sI); sI = MFMA(LImg.v, HImg.v, sI);
    sT = MFMA(HTxt.v, HTxt.v, sT); sT = MFMA(HTxt.v, LTxt.v, sT); sT = MFMA(LTxt.v, HTxt.v, sT);

    // ---- block-local exchange of img results, then dots ----
    shS1[w][lane] = sI;
    shGI[w][lane] = gI;
    __syncthreads();

    float p[8];
#pragma unroll
    for (int b = 0; b < 4; ++b) {
        const f32x4 s1 = shS1[b][lane];
        const f32x4 gi = shGI[b][lane];
        p[b]     = s1.x * gT.x + s1.y * gT.y + s1.z * gT.z + s1.w * gT.w;  // <S1[b], G_T>
        p[4 + b] = gi.x * sT.x + gi.y * sT.y + gi.z * sT.z + gi.w * sT.w;  // <S2, G_I[b]>
    }
#pragma unroll
    for (int off = 32; off; off >>= 1) {
#pragma unroll
        for (int q = 0; q < 8; ++q) p[q] += __shfl_down(p[q], off, 64);
    }
    if (lane == 0) {
        const float a = alp[0], sc = scale[0];
#pragma unroll
        for (int b = 0; b < 4; ++b) {
            const float d1 = -p[b] * (1.f / Kq);
            const float d2 = -p[4 + b] * (1.f / Kq);
            logits[b * Nq + n] = sc * (a * d1 + (1.f - a) * d2);
        }
    }
}

__global__ __launch_bounds__(256) void softmax_kernel(const float* __restrict__ logits,
                                                      const float* __restrict__ lsc,
                                                      float* __restrict__ out) {
    const int b   = blockIdx.x;
    const int tid = threadIdx.x;
    const float* row = logits + b * Nq;
    __shared__ float sh[4];
    float v[8];
    float mx = -INFINITY;
#pragma unroll
    for (int q = 0; q < 8; ++q) {
        v[q] = row[tid + q * 256];
        mx = fmaxf(mx, v[q]);
    }
#pragma unroll
    for (int off = 32; off; off >>= 1) mx = fmaxf(mx, __shfl_down(mx, off, 64));
    if ((tid & 63) == 0) sh[tid >> 6] = mx;
    __syncthreads();
    mx = fmaxf(fmaxf(sh[0], sh[1]), fmaxf(sh[2], sh[3]));

    float sum = 0.f;
#pragma unroll
    for (int q = 0; q < 8; ++q) sum += expf(v[q] - mx);
#pragma unroll
    for (int off = 32; off; off >>= 1) sum += __shfl_down(sum, off, 64);
    __syncthreads();
    if ((tid & 63) == 0) sh[tid >> 6] = sum;
    __syncthreads();
    sum = sh[0] + sh[1] + sh[2] + sh[3];

    const float lse = mx + logf(sum);
#pragma unroll
    for (int q = 0; q < 8; ++q) out[b * Nq + tid + q * 256] = v[q] - lse;
    if (b == 0 && tid == 0) out[Bq * Nq] = 1.f / (1.f + expf(-lsc[0]));
}

extern "C" void kernel_launch(void* const* d_in, const int* in_sizes, int n_in,
                              void* d_out, int out_size, void* d_ws, size_t ws_size,
                              hipStream_t stream) {
    const float* img   = (const float*)d_in[0];
    const float* text  = (const float*)d_in[1];
    const float* r     = (const float*)d_in[2];
    const float* alp   = (const float*)d_in[3];
    const float* scale = (const float*)d_in[4];
    const float* lsc   = (const float*)d_in[5];
    float* ws  = (float*)d_ws;   // logits: 4*2048 floats
    float* out = (float*)d_out;

    fused_kernel<<<Nq / 4, 256, 0, stream>>>(img, text, r, alp, scale, ws);
    softmax_kernel<<<Bq, 256, 0, stream>>>(ws, lsc, out);
}